// Round 9
// baseline (179.572 us; speedup 1.0000x reference)
//
#include <hip/hip_runtime.h>

// GraphProjection on MI355X (gfx950) — fused, global_load_lds, 2 blocks/CU.
// x:(8,512,64,64) f32, anchor/sigma:(128,512) f32.
// d_out = nodes (8,512,128) ++ soft_assign (8,128,256).
//
// Round 9: reg-staging abandoned (rounds 7/8: compiler spills prefetch regs
// across inline-asm barriers -> 300-470 MB scratch traffic). Back to round-6's
// spill-free global_load_lds staging, but SINGLE chunk buffer (32 KB) so LDS
// = 71 KB -> 2 blocks/CU; the second resident block's compute covers each
// stage stall (m114 cross-block overlap replaces intra-block double-buffer).

#define NCH 512
#define PARTS 4
#define NROWS 4   // rows per block

typedef __attribute__((address_space(3))) void lds_void_t;
typedef const __attribute__((address_space(1))) void gbl_void_t;

__device__ __forceinline__ void gload_lds16(const float* g, float* l) {
  __builtin_amdgcn_global_load_lds((gbl_void_t*)g, (lds_void_t*)l, 16, 0, 0);
}

// ---------------------------------------------------------------- prep
__global__ __launch_bounds__(512, 2)
void gp_prep(const float* __restrict__ anchor,
             const float* __restrict__ sigma,
             float* __restrict__ ws_anc) {   // [16][512][16]
  const int g = blockIdx.x;    // 0..15
  const int c = threadIdx.x;   // 0..511
  float vals[16];
#pragma unroll
  for (int k = 0; k < 8; ++k) {
    float a = anchor[((g << 3) + k) * NCH + c];
    float s = sigma [((g << 3) + k) * NCH + c];
    float r = 1.0f / s;
    vals[k]     = r;       // quads: q0=rs[0..3] q1=rs[4..7] q2=ars[0..3] q3=ars[4..7]
    vals[k + 8] = a * r;
  }
  float4* dst = (float4*)(ws_anc + (((size_t)g * NCH + c) << 4));
#pragma unroll
  for (int q = 0; q < 4; ++q) dst[q] = ((float4*)vals)[q];
}

// ---------------------------------------------------------------- fused main
struct SharedFused {
  float anc[NCH * 16];        // 32 KB  [c][16], quad q at pos q^((c>>4)&3)
  float chunk[NCH * 16];      // 32 KB  [c][16px], pixel-quad q at pos q^((c>>1)&3)
  float scratch[8 * 16 * 8];  // 4 KB   [wave][px][k]
  float soft[16 * 8];         // 512 B  [px][k] current row
  float soft_all[NROWS * 128];// 2 KB   [row][px][k]
};

__global__ __launch_bounds__(512, 2)
void gp_fused(const float* __restrict__ x,
              const float* __restrict__ ws_anc,
              float* __restrict__ soft_out,
              float* __restrict__ ws_s1) {
  __shared__ SharedFused sh;
  const int tid = threadIdx.x;
  const int bid = blockIdx.x;       // gx*128 + ((b*4+gy)*4 + part)
  const int gx   = bid >> 7;        // gx-siblings: equal bid%8 -> same XCD
  const int r    = bid & 127;
  const int part = r & 3;
  const int gy   = (r >> 2) & 3;
  const int b    = r >> 4;
  const int g    = (gy << 2) + gx;
  const int y0   = (gy << 4) + part * NROWS;
  const int x0   = gx << 4;
  const float* xb = x + (size_t)b * (NCH * 4096);

  // ---- stage anc table (32 KB) via global_load_lds
  {
    const float* tb = ws_anc + (size_t)g * (NCH * 16);
#pragma unroll
    for (int it = 0; it < 4; ++it) {
      int qf = it * 512 + tid;          // quad 0..2047
      int c  = qf >> 2;
      int p  = qf & 3;
      int ps = p ^ ((c >> 4) & 3);
      gload_lds16(tb + c * 16 + (ps << 2), &sh.anc[qf << 2]);
    }
  }

  auto stage = [&](int row) {           // one 16-px row (32 KB) -> chunk
#pragma unroll
    for (int it = 0; it < 4; ++it) {
      int qf = it * 512 + tid;
      int ci = qf >> 2;
      int qd = qf & 3;
      int qs = qd ^ ((ci >> 1) & 3);
      gload_lds16(xb + (size_t)ci * 4096 + (y0 + row) * 64 + x0 + (qs << 2),
                  &sh.chunk[qf << 2]);
    }
  };

  stage(0);
  asm volatile("s_waitcnt vmcnt(0) lgkmcnt(0)\ns_barrier" ::: "memory");

  float S1[8];
#pragma unroll
  for (int k = 0; k < 8; ++k) S1[k] = 0.0f;

  const int cg = tid >> 4, px = tid & 15;
  const int wv = tid >> 6, lane = tid & 63;
  const int asw = cg & 3;
  const int pq = px >> 2, pr = px & 3;
  const int csw2 = (tid >> 1) & 3;

#pragma unroll
  for (int rr = 0; rr < NROWS; ++rr) {
    // ---- pass 1: sq over this thread's 16 channels
    float sq[8];
#pragma unroll
    for (int k = 0; k < 8; ++k) sq[k] = 0.0f;
    {
      const float* ancb = sh.anc + cg * 256;
      const float* chb  = sh.chunk + (cg << 8);
#pragma unroll
      for (int i = 0; i < 16; ++i) {
        const float* ar = ancb + i * 16;
        float4 rlo = *(const float4*)(ar + ((0 ^ asw) << 2));
        float4 rhi = *(const float4*)(ar + ((1 ^ asw) << 2));
        float4 alo = *(const float4*)(ar + ((2 ^ asw) << 2));
        float4 ahi = *(const float4*)(ar + ((3 ^ asw) << 2));
        float xv = chb[(i << 4) + ((pq ^ ((i >> 1) & 3)) << 2) + pr];
        float t;
        t = fmaf(xv, rlo.x, -alo.x); sq[0] = fmaf(t, t, sq[0]);
        t = fmaf(xv, rlo.y, -alo.y); sq[1] = fmaf(t, t, sq[1]);
        t = fmaf(xv, rlo.z, -alo.z); sq[2] = fmaf(t, t, sq[2]);
        t = fmaf(xv, rlo.w, -alo.w); sq[3] = fmaf(t, t, sq[3]);
        t = fmaf(xv, rhi.x, -ahi.x); sq[4] = fmaf(t, t, sq[4]);
        t = fmaf(xv, rhi.y, -ahi.y); sq[5] = fmaf(t, t, sq[5]);
        t = fmaf(xv, rhi.z, -ahi.z); sq[6] = fmaf(t, t, sq[6]);
        t = fmaf(xv, rhi.w, -ahi.w); sq[7] = fmaf(t, t, sq[7]);
      }
    }
#pragma unroll
    for (int k = 0; k < 8; ++k) {      // combine wave's 4 channel-groups
      sq[k] += __shfl_xor(sq[k], 16, 64);
      sq[k] += __shfl_xor(sq[k], 32, 64);
    }
    if (lane < 16) {                   // lane == px
      *(float4*)&sh.scratch[((wv << 4) + lane) << 3]       =
          make_float4(sq[0], sq[1], sq[2], sq[3]);
      *(float4*)&sh.scratch[(((wv << 4) + lane) << 3) + 4] =
          make_float4(sq[4], sq[5], sq[6], sq[7]);
    }
    asm volatile("s_waitcnt lgkmcnt(0)\ns_barrier" ::: "memory");  // B2

    // ---- combine 8 waves + softmax; thread = (px2, k)
    if (tid < 128) {
      float acc = 0.0f;
#pragma unroll
      for (int w2 = 0; w2 < 8; ++w2) acc += sh.scratch[(w2 << 7) + tid];
      float l = -0.5f * acc;
      float mx = l;
      mx = fmaxf(mx, __shfl_xor(mx, 1, 64));
      mx = fmaxf(mx, __shfl_xor(mx, 2, 64));
      mx = fmaxf(mx, __shfl_xor(mx, 4, 64));
      float e = __expf(l - mx);
      float es = e;
      es += __shfl_xor(es, 1, 64);
      es += __shfl_xor(es, 2, 64);
      es += __shfl_xor(es, 4, 64);
      float sv = e / es;
      sh.soft[tid] = sv;
      sh.soft_all[(rr << 7) + tid] = sv;
    }
    asm volatile("s_waitcnt lgkmcnt(0)\ns_barrier" ::: "memory");  // B3

    // ---- pass 2: S1[k] += sum_px chunk[c][px] * soft[px][k]   (c = tid)
    {
      const float* ch = sh.chunk + (tid << 4);
#pragma unroll
      for (int qd = 0; qd < 4; ++qd) {
        float4 xv = *(const float4*)(ch + ((qd ^ csw2) << 2));
#pragma unroll
        for (int j = 0; j < 4; ++j) {
          float xvj = (j == 0) ? xv.x : (j == 1) ? xv.y : (j == 2) ? xv.z : xv.w;
          const float* sp = &sh.soft[((qd << 2) + j) << 3];
          float4 s0 = *(const float4*)sp;
          float4 s1 = *(const float4*)(sp + 4);
          S1[0] = fmaf(xvj, s0.x, S1[0]);
          S1[1] = fmaf(xvj, s0.y, S1[1]);
          S1[2] = fmaf(xvj, s0.z, S1[2]);
          S1[3] = fmaf(xvj, s0.w, S1[3]);
          S1[4] = fmaf(xvj, s1.x, S1[4]);
          S1[5] = fmaf(xvj, s1.y, S1[5]);
          S1[6] = fmaf(xvj, s1.z, S1[6]);
          S1[7] = fmaf(xvj, s1.w, S1[7]);
        }
      }
    }
    asm volatile("s_waitcnt lgkmcnt(0)\ns_barrier" ::: "memory");  // B4: all chunk
                                                                   // reads done
    if (rr + 1 < NROWS) {
      stage(rr + 1);   // overwrite chunk; other resident block computes meanwhile
      asm volatile("s_waitcnt vmcnt(0)\ns_barrier" ::: "memory");  // chunk ready
    }
  }

  // ---- epilogue: S1 partial (coalesced) + soft_assign from LDS
  const int bg = (b << 4) + g;
  {
    float* wp = ws_s1 + ((size_t)(bg * PARTS + part) << 3) * NCH + tid;
#pragma unroll
    for (int k = 0; k < 8; ++k) wp[k * NCH] = S1[k];
  }
  {
    // 512 threads cover k(8) x gpx(64): soft_out[k][part*64 + gpx]
    float* so = soft_out + (size_t)((b << 7) + (g << 3)) * 256 + part * 64;
    int k   = tid >> 6;
    int gpx = tid & 63;
    so[(size_t)k * 256 + gpx] =
        sh.soft_all[((gpx >> 4) << 7) + ((gpx & 15) << 3) + k];
  }
}

// ---------------------------------------------------------------- finalize
__global__ __launch_bounds__(512, 4)
void gp_final(const float* __restrict__ anchor,
              const float* __restrict__ sigma,
              const float* __restrict__ soft_out,
              const float* __restrict__ ws_s1,
              float* __restrict__ nodes_out) {
  const int bg = blockIdx.x;   // b*16+g
  const int b  = bg >> 4, g = bg & 15;
  const int tid = threadIdx.x; // channel c
  __shared__ float sS0[8];
  __shared__ float red[8 * 8];
  __shared__ float invn[8];

  if (tid < 256) {
    int k = tid >> 5, sl = tid & 31;
    const float* sp = soft_out + (size_t)((b << 7) + (g << 3) + k) * 256 + (sl << 3);
    float4 a0 = *(const float4*)sp;
    float4 a1 = *(const float4*)(sp + 4);
    float v = a0.x + a0.y + a0.z + a0.w + a1.x + a1.y + a1.z + a1.w;
    v += __shfl_xor(v, 1, 64);
    v += __shfl_xor(v, 2, 64);
    v += __shfl_xor(v, 4, 64);
    v += __shfl_xor(v, 8, 64);
    v += __shfl_xor(v, 16, 64);
    if (sl == 0) sS0[k] = v;
  }
  __syncthreads();

  float S1[8];
#pragma unroll
  for (int k = 0; k < 8; ++k) S1[k] = 0.0f;
#pragma unroll
  for (int pt = 0; pt < PARTS; ++pt) {
    const float* wp = ws_s1 + ((size_t)(bg * PARTS + pt) << 3) * NCH + tid;
#pragma unroll
    for (int k = 0; k < 8; ++k) S1[k] += wp[k * NCH];
  }

  float v[8];
#pragma unroll
  for (int k = 0; k < 8; ++k) {
    float s  = sigma [((g << 3) + k) * NCH + tid];
    float a  = anchor[((g << 3) + k) * NCH + tid];
    float rs = 1.0f / s;
    float S0 = sS0[k];
    float nd = rs * S1[k] - (a * rs) * S0;
    v[k] = nd / (S0 + 1e-9f);
  }

  const int wv = tid >> 6, lane = tid & 63;
#pragma unroll
  for (int k = 0; k < 8; ++k) {
    float s = v[k] * v[k];
    s += __shfl_xor(s, 1, 64);
    s += __shfl_xor(s, 2, 64);
    s += __shfl_xor(s, 4, 64);
    s += __shfl_xor(s, 8, 64);
    s += __shfl_xor(s, 16, 64);
    s += __shfl_xor(s, 32, 64);
    if (lane == 0) red[(wv << 3) + k] = s;
  }
  __syncthreads();
  if (tid < 8) {
    float t2 = 0.0f;
#pragma unroll
    for (int w = 0; w < 8; ++w) t2 += red[(w << 3) + tid];
    invn[tid] = 1.0f / fmaxf(sqrtf(t2), 1e-12f);
  }
  __syncthreads();

  float4 o0 = make_float4(v[0] * invn[0], v[1] * invn[1], v[2] * invn[2], v[3] * invn[3]);
  float4 o1 = make_float4(v[4] * invn[4], v[5] * invn[5], v[6] * invn[6], v[7] * invn[7]);
  float* dst = nodes_out + ((size_t)(b * NCH) + tid) * 128 + (g << 3);
  *(float4*)(dst)     = o0;
  *(float4*)(dst + 4) = o1;
}

extern "C" void kernel_launch(void* const* d_in, const int* in_sizes, int n_in,
                              void* d_out, int out_size, void* d_ws, size_t ws_size,
                              hipStream_t stream) {
  const float* x      = (const float*)d_in[0];
  const float* anchor = (const float*)d_in[1];
  const float* sigma  = (const float*)d_in[2];
  float* out = (float*)d_out;
  float* wsf = (float*)d_ws;

  const size_t n_nodes = 524288;           // 8*512*128
  float* soft_out = out + n_nodes;
  float* ws_anc = wsf;                     // 16*512*16 = 131072 floats (512 KB)
  float* ws_s1  = wsf + 131072;            // 128*4*8*512 floats (8 MB)

  gp_prep <<<16,  512, 0, stream>>>(anchor, sigma, ws_anc);
  gp_fused<<<512, 512, 0, stream>>>(x, ws_anc, soft_out, ws_s1);
  gp_final<<<128, 512, 0, stream>>>(anchor, sigma, soft_out, ws_s1, out);
}

// Round 10
// 52.289 us; speedup vs baseline: 3.4342x; 3.4342x over previous
//
#include <hip/hip_runtime.h>

// GraphProjection on MI355X (gfx950) — fused, global_load_lds, 2 blocks/CU.
// x:(8,512,64,64) f32, anchor/sigma:(128,512) f32.
// d_out = nodes (8,512,128) ++ soft_assign (8,128,256).
//
// Round 10 = round 9 with ONE change: `#pragma unroll 1` on the row loop.
// Evidence: rounds 8 and 9 (different staging schemes, same `#pragma unroll`
// on the 4-iter row loop) produced byte-identical 304 MB scratch WRITE_SIZE;
// round 6 (no unroll pragma) was clean at 88 VGPR / 5 MB. The full unroll of
// 4 row bodies (each with unrolled 16-iter pass-1 + 4 asm barriers) blows up
// live ranges -> spill. Forcing no-unroll restores round-6 codegen with this
// round's 71-KB LDS (2 blocks/CU) layout.

#define NCH 512
#define PARTS 4
#define NROWS 4   // rows per block

typedef __attribute__((address_space(3))) void lds_void_t;
typedef const __attribute__((address_space(1))) void gbl_void_t;

__device__ __forceinline__ void gload_lds16(const float* g, float* l) {
  __builtin_amdgcn_global_load_lds((gbl_void_t*)g, (lds_void_t*)l, 16, 0, 0);
}

// ---------------------------------------------------------------- prep
__global__ __launch_bounds__(512, 2)
void gp_prep(const float* __restrict__ anchor,
             const float* __restrict__ sigma,
             float* __restrict__ ws_anc) {   // [16][512][16]
  const int g = blockIdx.x;    // 0..15
  const int c = threadIdx.x;   // 0..511
  float vals[16];
#pragma unroll
  for (int k = 0; k < 8; ++k) {
    float a = anchor[((g << 3) + k) * NCH + c];
    float s = sigma [((g << 3) + k) * NCH + c];
    float r = 1.0f / s;
    vals[k]     = r;       // quads: q0=rs[0..3] q1=rs[4..7] q2=ars[0..3] q3=ars[4..7]
    vals[k + 8] = a * r;
  }
  float4* dst = (float4*)(ws_anc + (((size_t)g * NCH + c) << 4));
#pragma unroll
  for (int q = 0; q < 4; ++q) dst[q] = ((float4*)vals)[q];
}

// ---------------------------------------------------------------- fused main
struct SharedFused {
  float anc[NCH * 16];        // 32 KB  [c][16], quad q at pos q^((c>>4)&3)
  float chunk[NCH * 16];      // 32 KB  [c][16px], pixel-quad q at pos q^((c>>1)&3)
  float scratch[8 * 16 * 8];  // 4 KB   [wave][px][k]
  float soft[16 * 8];         // 512 B  [px][k] current row
  float soft_all[NROWS * 128];// 2 KB   [row][px][k]
};

__global__ __launch_bounds__(512, 2)
void gp_fused(const float* __restrict__ x,
              const float* __restrict__ ws_anc,
              float* __restrict__ soft_out,
              float* __restrict__ ws_s1) {
  __shared__ SharedFused sh;
  const int tid = threadIdx.x;
  const int bid = blockIdx.x;       // gx*128 + ((b*4+gy)*4 + part)
  const int gx   = bid >> 7;        // gx-siblings: equal bid%8 -> same XCD
  const int r    = bid & 127;
  const int part = r & 3;
  const int gy   = (r >> 2) & 3;
  const int b    = r >> 4;
  const int g    = (gy << 2) + gx;
  const int y0   = (gy << 4) + part * NROWS;
  const int x0   = gx << 4;
  const float* xb = x + (size_t)b * (NCH * 4096);

  // ---- stage anc table (32 KB) via global_load_lds
  {
    const float* tb = ws_anc + (size_t)g * (NCH * 16);
#pragma unroll
    for (int it = 0; it < 4; ++it) {
      int qf = it * 512 + tid;          // quad 0..2047
      int c  = qf >> 2;
      int p  = qf & 3;
      int ps = p ^ ((c >> 4) & 3);
      gload_lds16(tb + c * 16 + (ps << 2), &sh.anc[qf << 2]);
    }
  }

  auto stage = [&](int row) {           // one 16-px row (32 KB) -> chunk
#pragma unroll
    for (int it = 0; it < 4; ++it) {
      int qf = it * 512 + tid;
      int ci = qf >> 2;
      int qd = qf & 3;
      int qs = qd ^ ((ci >> 1) & 3);
      gload_lds16(xb + (size_t)ci * 4096 + (y0 + row) * 64 + x0 + (qs << 2),
                  &sh.chunk[qf << 2]);
    }
  };

  stage(0);
  asm volatile("s_waitcnt vmcnt(0) lgkmcnt(0)\ns_barrier" ::: "memory");

  float S1[8];
#pragma unroll
  for (int k = 0; k < 8; ++k) S1[k] = 0.0f;

  const int cg = tid >> 4, px = tid & 15;
  const int wv = tid >> 6, lane = tid & 63;
  const int asw = cg & 3;
  const int pq = px >> 2, pr = px & 3;
  const int csw2 = (tid >> 1) & 3;

#pragma unroll 1
  for (int rr = 0; rr < NROWS; ++rr) {
    // ---- pass 1: sq over this thread's 16 channels
    float sq[8];
#pragma unroll
    for (int k = 0; k < 8; ++k) sq[k] = 0.0f;
    {
      const float* ancb = sh.anc + cg * 256;
      const float* chb  = sh.chunk + (cg << 8);
#pragma unroll
      for (int i = 0; i < 16; ++i) {
        const float* ar = ancb + i * 16;
        float4 rlo = *(const float4*)(ar + ((0 ^ asw) << 2));
        float4 rhi = *(const float4*)(ar + ((1 ^ asw) << 2));
        float4 alo = *(const float4*)(ar + ((2 ^ asw) << 2));
        float4 ahi = *(const float4*)(ar + ((3 ^ asw) << 2));
        float xv = chb[(i << 4) + ((pq ^ ((i >> 1) & 3)) << 2) + pr];
        float t;
        t = fmaf(xv, rlo.x, -alo.x); sq[0] = fmaf(t, t, sq[0]);
        t = fmaf(xv, rlo.y, -alo.y); sq[1] = fmaf(t, t, sq[1]);
        t = fmaf(xv, rlo.z, -alo.z); sq[2] = fmaf(t, t, sq[2]);
        t = fmaf(xv, rlo.w, -alo.w); sq[3] = fmaf(t, t, sq[3]);
        t = fmaf(xv, rhi.x, -ahi.x); sq[4] = fmaf(t, t, sq[4]);
        t = fmaf(xv, rhi.y, -ahi.y); sq[5] = fmaf(t, t, sq[5]);
        t = fmaf(xv, rhi.z, -ahi.z); sq[6] = fmaf(t, t, sq[6]);
        t = fmaf(xv, rhi.w, -ahi.w); sq[7] = fmaf(t, t, sq[7]);
      }
    }
#pragma unroll
    for (int k = 0; k < 8; ++k) {      // combine wave's 4 channel-groups
      sq[k] += __shfl_xor(sq[k], 16, 64);
      sq[k] += __shfl_xor(sq[k], 32, 64);
    }
    if (lane < 16) {                   // lane == px
      *(float4*)&sh.scratch[((wv << 4) + lane) << 3]       =
          make_float4(sq[0], sq[1], sq[2], sq[3]);
      *(float4*)&sh.scratch[(((wv << 4) + lane) << 3) + 4] =
          make_float4(sq[4], sq[5], sq[6], sq[7]);
    }
    asm volatile("s_waitcnt lgkmcnt(0)\ns_barrier" ::: "memory");  // B2

    // ---- combine 8 waves + softmax; thread = (px2, k)
    if (tid < 128) {
      float acc = 0.0f;
#pragma unroll
      for (int w2 = 0; w2 < 8; ++w2) acc += sh.scratch[(w2 << 7) + tid];
      float l = -0.5f * acc;
      float mx = l;
      mx = fmaxf(mx, __shfl_xor(mx, 1, 64));
      mx = fmaxf(mx, __shfl_xor(mx, 2, 64));
      mx = fmaxf(mx, __shfl_xor(mx, 4, 64));
      float e = __expf(l - mx);
      float es = e;
      es += __shfl_xor(es, 1, 64);
      es += __shfl_xor(es, 2, 64);
      es += __shfl_xor(es, 4, 64);
      float sv = e / es;
      sh.soft[tid] = sv;
      sh.soft_all[(rr << 7) + tid] = sv;
    }
    asm volatile("s_waitcnt lgkmcnt(0)\ns_barrier" ::: "memory");  // B3

    // ---- pass 2: S1[k] += sum_px chunk[c][px] * soft[px][k]   (c = tid)
    {
      const float* ch = sh.chunk + (tid << 4);
#pragma unroll
      for (int qd = 0; qd < 4; ++qd) {
        float4 xv = *(const float4*)(ch + ((qd ^ csw2) << 2));
#pragma unroll
        for (int j = 0; j < 4; ++j) {
          float xvj = (j == 0) ? xv.x : (j == 1) ? xv.y : (j == 2) ? xv.z : xv.w;
          const float* sp = &sh.soft[((qd << 2) + j) << 3];
          float4 s0 = *(const float4*)sp;
          float4 s1 = *(const float4*)(sp + 4);
          S1[0] = fmaf(xvj, s0.x, S1[0]);
          S1[1] = fmaf(xvj, s0.y, S1[1]);
          S1[2] = fmaf(xvj, s0.z, S1[2]);
          S1[3] = fmaf(xvj, s0.w, S1[3]);
          S1[4] = fmaf(xvj, s1.x, S1[4]);
          S1[5] = fmaf(xvj, s1.y, S1[5]);
          S1[6] = fmaf(xvj, s1.z, S1[6]);
          S1[7] = fmaf(xvj, s1.w, S1[7]);
        }
      }
    }
    asm volatile("s_waitcnt lgkmcnt(0)\ns_barrier" ::: "memory");  // B4: all chunk
                                                                   // reads done
    if (rr + 1 < NROWS) {
      stage(rr + 1);   // overwrite chunk; other resident block computes meanwhile
      asm volatile("s_waitcnt vmcnt(0)\ns_barrier" ::: "memory");  // chunk ready
    }
  }

  // ---- epilogue: S1 partial (coalesced) + soft_assign from LDS
  const int bg = (b << 4) + g;
  {
    float* wp = ws_s1 + ((size_t)(bg * PARTS + part) << 3) * NCH + tid;
#pragma unroll
    for (int k = 0; k < 8; ++k) wp[k * NCH] = S1[k];
  }
  {
    // 512 threads cover k(8) x gpx(64): soft_out[k][part*64 + gpx]
    float* so = soft_out + (size_t)((b << 7) + (g << 3)) * 256 + part * 64;
    int k   = tid >> 6;
    int gpx = tid & 63;
    so[(size_t)k * 256 + gpx] =
        sh.soft_all[((gpx >> 4) << 7) + ((gpx & 15) << 3) + k];
  }
}

// ---------------------------------------------------------------- finalize
__global__ __launch_bounds__(512, 4)
void gp_final(const float* __restrict__ anchor,
              const float* __restrict__ sigma,
              const float* __restrict__ soft_out,
              const float* __restrict__ ws_s1,
              float* __restrict__ nodes_out) {
  const int bg = blockIdx.x;   // b*16+g
  const int b  = bg >> 4, g = bg & 15;
  const int tid = threadIdx.x; // channel c
  __shared__ float sS0[8];
  __shared__ float red[8 * 8];
  __shared__ float invn[8];

  if (tid < 256) {
    int k = tid >> 5, sl = tid & 31;
    const float* sp = soft_out + (size_t)((b << 7) + (g << 3) + k) * 256 + (sl << 3);
    float4 a0 = *(const float4*)sp;
    float4 a1 = *(const float4*)(sp + 4);
    float v = a0.x + a0.y + a0.z + a0.w + a1.x + a1.y + a1.z + a1.w;
    v += __shfl_xor(v, 1, 64);
    v += __shfl_xor(v, 2, 64);
    v += __shfl_xor(v, 4, 64);
    v += __shfl_xor(v, 8, 64);
    v += __shfl_xor(v, 16, 64);
    if (sl == 0) sS0[k] = v;
  }
  __syncthreads();

  float S1[8];
#pragma unroll
  for (int k = 0; k < 8; ++k) S1[k] = 0.0f;
#pragma unroll
  for (int pt = 0; pt < PARTS; ++pt) {
    const float* wp = ws_s1 + ((size_t)(bg * PARTS + pt) << 3) * NCH + tid;
#pragma unroll
    for (int k = 0; k < 8; ++k) S1[k] += wp[k * NCH];
  }

  float v[8];
#pragma unroll
  for (int k = 0; k < 8; ++k) {
    float s  = sigma [((g << 3) + k) * NCH + tid];
    float a  = anchor[((g << 3) + k) * NCH + tid];
    float rs = 1.0f / s;
    float S0 = sS0[k];
    float nd = rs * S1[k] - (a * rs) * S0;
    v[k] = nd / (S0 + 1e-9f);
  }

  const int wv = tid >> 6, lane = tid & 63;
#pragma unroll
  for (int k = 0; k < 8; ++k) {
    float s = v[k] * v[k];
    s += __shfl_xor(s, 1, 64);
    s += __shfl_xor(s, 2, 64);
    s += __shfl_xor(s, 4, 64);
    s += __shfl_xor(s, 8, 64);
    s += __shfl_xor(s, 16, 64);
    s += __shfl_xor(s, 32, 64);
    if (lane == 0) red[(wv << 3) + k] = s;
  }
  __syncthreads();
  if (tid < 8) {
    float t2 = 0.0f;
#pragma unroll
    for (int w = 0; w < 8; ++w) t2 += red[(w << 3) + tid];
    invn[tid] = 1.0f / fmaxf(sqrtf(t2), 1e-12f);
  }
  __syncthreads();

  float4 o0 = make_float4(v[0] * invn[0], v[1] * invn[1], v[2] * invn[2], v[3] * invn[3]);
  float4 o1 = make_float4(v[4] * invn[4], v[5] * invn[5], v[6] * invn[6], v[7] * invn[7]);
  float* dst = nodes_out + ((size_t)(b * NCH) + tid) * 128 + (g << 3);
  *(float4*)(dst)     = o0;
  *(float4*)(dst + 4) = o1;
}

extern "C" void kernel_launch(void* const* d_in, const int* in_sizes, int n_in,
                              void* d_out, int out_size, void* d_ws, size_t ws_size,
                              hipStream_t stream) {
  const float* x      = (const float*)d_in[0];
  const float* anchor = (const float*)d_in[1];
  const float* sigma  = (const float*)d_in[2];
  float* out = (float*)d_out;
  float* wsf = (float*)d_ws;

  const size_t n_nodes = 524288;           // 8*512*128
  float* soft_out = out + n_nodes;
  float* ws_anc = wsf;                     // 16*512*16 = 131072 floats (512 KB)
  float* ws_s1  = wsf + 131072;            // 128*4*8*512 floats (8 MB)

  gp_prep <<<16,  512, 0, stream>>>(anchor, sigma, ws_anc);
  gp_fused<<<512, 512, 0, stream>>>(x, ws_anc, soft_out, ws_s1);
  gp_final<<<128, 512, 0, stream>>>(anchor, sigma, soft_out, ws_s1, out);
}